// Round 2
// baseline (479.485 us; speedup 1.0000x reference)
//
#include <hip/hip_runtime.h>
#include <cstdint>
#include <cstddef>

#define BATCH 4096
#define HID   2048
#define KTOT  4096
#define BM    128
#define BH    32
#define BK    64
#define NKT   (KTOT / BK)   // 64

typedef __attribute__((ext_vector_type(8))) short bf16x8;
typedef __attribute__((ext_vector_type(4))) float f32x4;

__device__ __forceinline__ unsigned short f2bf(float f) {
  union { float f; unsigned u; } a; a.f = f;
  unsigned u = a.u;
  return (unsigned short)((u + 0x7FFFu + ((u >> 16) & 1u)) >> 16);  // RNE
}

__device__ __forceinline__ void gload_lds16(const void* g, void* l) {
  __builtin_amdgcn_global_load_lds((const __attribute__((address_space(1))) void*)g,
                                   (__attribute__((address_space(3))) void*)l, 16, 0, 0);
}

// ---- fp32 -> bf16 pack: A = [x | h] (4096x4096), W = [Wi;Wf;Wg;Wo | x/h] (8192x4096)
// 12 segments of 2048x2048 elements each:
//   0,1: x rows 0-2047 / 2048-4095   -> Abf cols 0-2047
//   2,3: h rows 0-2047 / 2048-4095   -> Abf cols 2048-4095
//   4-7: Wx (i,f,g,o)                -> Wbf[g*2048 ..][cols 0-2047]
//   8-11: Wh (i,f,g,o)               -> Wbf[g*2048 ..][cols 2048-4095]
__global__ __launch_bounds__(256) void convert_kernel(
    const float* __restrict__ x, const float* __restrict__ h,
    const float* __restrict__ wii, const float* __restrict__ wif,
    const float* __restrict__ wig, const float* __restrict__ wio,
    const float* __restrict__ whi, const float* __restrict__ whf,
    const float* __restrict__ whg, const float* __restrict__ who,
    unsigned short* __restrict__ Abf, unsigned short* __restrict__ Wbf) {
  int seg = blockIdx.y;
  const float* src;
  unsigned short* dst;
  int ofs;        // column offset in packed dst
  size_t rofs;    // row offset in packed dst
  if (seg < 4) {
    src = (seg < 2) ? x : h;
    dst = Abf;
    ofs = (seg < 2) ? 0 : 2048;
    rofs = (seg & 1) ? 2048 : 0;
    src += rofs * 2048;            // second half of the 4096 batch rows
  } else {
    int g = (seg - 4) & 3;
    dst = Wbf + (size_t)g * 2048 * 4096;
    ofs = (seg >= 8) ? 2048 : 0;
    rofs = 0;
    switch (seg) {
      case 4: src = wii; break; case 5: src = wif; break;
      case 6: src = wig; break; case 7: src = wio; break;
      case 8: src = whi; break; case 9: src = whf; break;
      case 10: src = whg; break; default: src = who; break;
    }
  }
  size_t idx = (size_t)blockIdx.x * 256 + threadIdx.x;  // 1,048,576 threads/seg
  size_t e = idx * 4;                                    // 4,194,304 elems/seg
  int n = (int)(e >> 11);
  int k = (int)(e & 2047);
  float4 v = *(const float4*)(src + e);
  ushort4 o;
  o.x = f2bf(v.x); o.y = f2bf(v.y); o.z = f2bf(v.z); o.w = f2bf(v.w);
  *(ushort4*)(dst + (rofs + (size_t)n) * 4096 + ofs + k) = o;
}

// ---- fused LSTM GEMM: gates = A @ Wcat^T, epilogue in-thread.
// Block: 128 M-rows x (4 gates x 32 H-cols). Waves: 2(M) x 2(H-halves of 16).
// B_lds row rb = gate*32 + jj  <->  Wcat row gate*2048 + j0 + jj.
// acc[mf][gate]: lane holds col j = j0 + wc*16 + (lane&15) for ALL 4 gates -> local epilogue.
template<int MODE>
__global__ __launch_bounds__(256) void lstm_gemm(
    const unsigned short* __restrict__ Abf, const unsigned short* __restrict__ Wbf,
    const float* __restrict__ x, const float* __restrict__ h,
    const float* __restrict__ wii, const float* __restrict__ wif,
    const float* __restrict__ wig, const float* __restrict__ wio,
    const float* __restrict__ whi, const float* __restrict__ whf,
    const float* __restrict__ whg, const float* __restrict__ who,
    const float* __restrict__ c_in,
    const float* __restrict__ bias_i, const float* __restrict__ bias_f,
    const float* __restrict__ bias_g, const float* __restrict__ bias_o,
    float* __restrict__ out) {
  __shared__ unsigned short Ald[BM * BK];   // 16 KB, row-major [128][64]
  __shared__ unsigned short Bld[128 * BK];  // 16 KB, row rb = gate*32+jj

  int tid = threadIdx.x;
  int lane = tid & 63;
  int wid = tid >> 6;
  int wr = wid >> 1, wc = wid & 1;

  int bid = blockIdx.x;                    // 2048 blocks
  int swz = (bid & 7) * 256 + (bid >> 3);  // bijective XCD swizzle (2048 = 8*256)
  int mt = swz & 31;                       // 32 M-tiles; consecutive swz share ht -> W panel L2-hot
  int ht = swz >> 5;                       // 64 H-tiles
  int m0 = mt * BM;
  int j0 = ht * BH;

  f32x4 acc[4][4];
  #pragma unroll
  for (int a = 0; a < 4; a++)
    #pragma unroll
    for (int b = 0; b < 4; b++) acc[a][b] = (f32x4){0.f, 0.f, 0.f, 0.f};

  int lrow = lane & 15;
  int lk8 = (lane >> 4) * 8;

  for (int kt = 0; kt < NKT; kt++) {
    int k0 = kt * BK;
    if (MODE == 0) {
      // async global->LDS, 16B/lane; LDS dest linear in thread order (wave base + lane*16)
      #pragma unroll
      for (int i = 0; i < 4; i++) {
        int c = i * 256 + tid;
        int r = c >> 3, cc = c & 7;
        gload_lds16(Abf + (size_t)(m0 + r) * 4096 + k0 + cc * 8,
                    (char*)Ald + (size_t)c * 16);
      }
      #pragma unroll
      for (int i = 0; i < 4; i++) {
        int c = i * 256 + tid;
        int rb = c >> 3, cc = c & 7;
        int wrow = (rb >> 5) * 2048 + j0 + (rb & 31);
        gload_lds16(Wbf + (size_t)wrow * 4096 + k0 + cc * 8,
                    (char*)Bld + (size_t)c * 16);
      }
    } else {
      // fallback: reg-staged fp32 load + convert + ds_write (no workspace needed)
      const float* Asrc = (k0 < 2048) ? x : h;
      int ka = k0 & 2047;
      #pragma unroll
      for (int i = 0; i < 4; i++) {
        int c = i * 256 + tid;
        int r = c >> 3, cc = c & 7;
        const float* s = Asrc + (size_t)(m0 + r) * 2048 + ka + cc * 8;
        float4 v0 = *(const float4*)s;
        float4 v1 = *(const float4*)(s + 4);
        bf16x8 pk;
        pk[0] = (short)f2bf(v0.x); pk[1] = (short)f2bf(v0.y);
        pk[2] = (short)f2bf(v0.z); pk[3] = (short)f2bf(v0.w);
        pk[4] = (short)f2bf(v1.x); pk[5] = (short)f2bf(v1.y);
        pk[6] = (short)f2bf(v1.z); pk[7] = (short)f2bf(v1.w);
        *(bf16x8*)((char*)Ald + (size_t)c * 16) = pk;
      }
      #pragma unroll
      for (int i = 0; i < 4; i++) {
        int c = i * 256 + tid;
        int rb = c >> 3, cc = c & 7;
        int g = rb >> 5, jj = rb & 31;
        const float* Bsrc;
        if (k0 < 2048) Bsrc = (g == 0) ? wii : (g == 1) ? wif : (g == 2) ? wig : wio;
        else           Bsrc = (g == 0) ? whi : (g == 1) ? whf : (g == 2) ? whg : who;
        const float* s = Bsrc + (size_t)(j0 + jj) * 2048 + ka + cc * 8;
        float4 v0 = *(const float4*)s;
        float4 v1 = *(const float4*)(s + 4);
        bf16x8 pk;
        pk[0] = (short)f2bf(v0.x); pk[1] = (short)f2bf(v0.y);
        pk[2] = (short)f2bf(v0.z); pk[3] = (short)f2bf(v0.w);
        pk[4] = (short)f2bf(v1.x); pk[5] = (short)f2bf(v1.y);
        pk[6] = (short)f2bf(v1.z); pk[7] = (short)f2bf(v1.w);
        *(bf16x8*)((char*)Bld + (size_t)c * 16) = pk;
      }
    }
    __syncthreads();   // drains vmcnt (global_load_lds) / lgkm (ds_write)

    #pragma unroll
    for (int ks = 0; ks < 2; ks++) {
      bf16x8 af[4], bg[4];
      #pragma unroll
      for (int mf = 0; mf < 4; mf++)
        af[mf] = *(const bf16x8*)&Ald[(wr * 64 + mf * 16 + lrow) * 64 + ks * 32 + lk8];
      #pragma unroll
      for (int g = 0; g < 4; g++)
        bg[g] = *(const bf16x8*)&Bld[(g * 32 + wc * 16 + lrow) * 64 + ks * 32 + lk8];
      #pragma unroll
      for (int mf = 0; mf < 4; mf++)
        #pragma unroll
        for (int g = 0; g < 4; g++)
          acc[mf][g] = __builtin_amdgcn_mfma_f32_16x16x32_bf16(af[mf], bg[g], acc[mf][g], 0, 0, 0);
    }
    __syncthreads();   // protect LDS before next stage overwrites
  }

  // ---- epilogue: all 4 gates for (m, j) are thread-local
  int j = j0 + wc * 16 + lrow;
  float bi = bias_i[j], bff = bias_f[j], bgg = bias_g[j], bo = bias_o[j];
  int rbase = m0 + wr * 64 + (lane >> 4) * 4;
  #pragma unroll
  for (int mf = 0; mf < 4; mf++) {
    #pragma unroll
    for (int q = 0; q < 4; q++) {
      int m = rbase + mf * 16 + q;          // C/D layout: col=lane&15, row=(lane>>4)*4+q
      size_t off = (size_t)m * HID + j;
      float gi = acc[mf][0][q] + bi;
      float gf = acc[mf][1][q] + bff;
      float gg = acc[mf][2][q] + bgg;
      float go = acc[mf][3][q] + bo;
      float iv = 1.f / (1.f + __expf(-gi));
      float fv = 1.f / (1.f + __expf(-gf));
      float gv = tanhf(gg);
      float ov = 1.f / (1.f + __expf(-go));
      float cn = fv * c_in[off] + iv * gv;
      float hn = ov * tanhf(cn);
      out[off] = hn;                                 // h_new
      out[(size_t)BATCH * HID + off] = cn;           // c_new
    }
  }
}

extern "C" void kernel_launch(void* const* d_in, const int* in_sizes, int n_in,
                              void* d_out, int out_size, void* d_ws, size_t ws_size,
                              hipStream_t stream) {
  const float* x   = (const float*)d_in[0];
  const float* h   = (const float*)d_in[1];
  const float* c   = (const float*)d_in[2];
  const float* wii = (const float*)d_in[3];
  const float* wif = (const float*)d_in[4];
  const float* wig = (const float*)d_in[5];
  const float* wio = (const float*)d_in[6];
  const float* whi = (const float*)d_in[7];
  const float* whf = (const float*)d_in[8];
  const float* whg = (const float*)d_in[9];
  const float* who = (const float*)d_in[10];
  const float* bi  = (const float*)d_in[11];
  const float* bf  = (const float*)d_in[12];
  const float* bg  = (const float*)d_in[13];
  const float* bo  = (const float*)d_in[14];
  float* out = (float*)d_out;

  size_t needA = (size_t)4096 * 4096 * 2;   // 32 MB bf16
  size_t needW = (size_t)8192 * 4096 * 2;   // 64 MB bf16

  if (ws_size >= needA + needW) {
    unsigned short* Abf = (unsigned short*)d_ws;
    unsigned short* Wbf = (unsigned short*)((char*)d_ws + needA);
    convert_kernel<<<dim3(4096, 12), 256, 0, stream>>>(
        x, h, wii, wif, wig, wio, whi, whf, whg, who, Abf, Wbf);
    lstm_gemm<0><<<2048, 256, 0, stream>>>(
        Abf, Wbf, x, h, wii, wif, wig, wio, whi, whf, whg, who,
        c, bi, bf, bg, bo, out);
  } else {
    lstm_gemm<1><<<2048, 256, 0, stream>>>(
        nullptr, nullptr, x, h, wii, wif, wig, wio, whi, whf, whg, who,
        c, bi, bf, bg, bo, out);
  }
}

// Round 3
// 413.457 us; speedup vs baseline: 1.1597x; 1.1597x over previous
//
#include <hip/hip_runtime.h>
#include <cstdint>
#include <cstddef>

#define BATCH 4096
#define HID   2048
#define KTOT  4096
#define BM    128
#define BH    32
#define BK    64
#define NKT   (KTOT / BK)   // 64

typedef __attribute__((ext_vector_type(8))) short bf16x8;
typedef __attribute__((ext_vector_type(4))) float f32x4;

__device__ __forceinline__ unsigned short f2bf(float f) {
  union { float f; unsigned u; } a; a.f = f;
  unsigned u = a.u;
  return (unsigned short)((u + 0x7FFFu + ((u >> 16) & 1u)) >> 16);  // RNE
}

__device__ __forceinline__ void gload_lds16(const void* g, void* l) {
  __builtin_amdgcn_global_load_lds((const __attribute__((address_space(1))) void*)g,
                                   (__attribute__((address_space(3))) void*)l, 16, 0, 0);
}

// ---- fp32 -> bf16 pack: A = [x | h] (4096x4096), W = [Wi;Wf;Wg;Wo | x/h] (8192x4096)
// 12 segments of 2048x2048 elements each.
__global__ __launch_bounds__(256) void convert_kernel(
    const float* __restrict__ x, const float* __restrict__ h,
    const float* __restrict__ wii, const float* __restrict__ wif,
    const float* __restrict__ wig, const float* __restrict__ wio,
    const float* __restrict__ whi, const float* __restrict__ whf,
    const float* __restrict__ whg, const float* __restrict__ who,
    unsigned short* __restrict__ Abf, unsigned short* __restrict__ Wbf) {
  int seg = blockIdx.y;
  const float* src;
  unsigned short* dst;
  int ofs;        // column offset in packed dst
  size_t rofs;    // row offset in packed dst
  if (seg < 4) {
    src = (seg < 2) ? x : h;
    dst = Abf;
    ofs = (seg < 2) ? 0 : 2048;
    rofs = (seg & 1) ? 2048 : 0;
    src += rofs * 2048;            // second half of the 4096 batch rows
  } else {
    int g = (seg - 4) & 3;
    dst = Wbf + (size_t)g * 2048 * 4096;
    ofs = (seg >= 8) ? 2048 : 0;
    rofs = 0;
    switch (seg) {
      case 4: src = wii; break; case 5: src = wif; break;
      case 6: src = wig; break; case 7: src = wio; break;
      case 8: src = whi; break; case 9: src = whf; break;
      case 10: src = whg; break; default: src = who; break;
    }
  }
  size_t idx = (size_t)blockIdx.x * 256 + threadIdx.x;  // 1,048,576 threads/seg
  size_t e = idx * 4;                                    // 4,194,304 elems/seg
  int n = (int)(e >> 11);
  int k = (int)(e & 2047);
  float4 v = *(const float4*)(src + e);
  ushort4 o;
  o.x = f2bf(v.x); o.y = f2bf(v.y); o.z = f2bf(v.z); o.w = f2bf(v.w);
  *(ushort4*)(dst + (rofs + (size_t)n) * 4096 + ofs + k) = o;
}

// ---- fused LSTM GEMM: gates = A @ Wcat^T, epilogue in-thread.
// Block: 128 M-rows x (4 gates x 32 H-cols). Waves: 2(M) x 2(H-halves of 16).
// T2 LDS swizzle: 16B-chunk index ^= (row & 7).
//   - global_load_lds dest stays LINEAR (HW requirement); the global SOURCE
//     chunk is cc ^ (r&7) (involution -> source-permute == inverse-permute).
//   - ds_read address uses chunk (q ^ (lrow&7)); row&7 == lrow&7 because all
//     row-base terms are multiples of 8.
template<int MODE>
__global__ __launch_bounds__(256) void lstm_gemm(
    const unsigned short* __restrict__ Abf, const unsigned short* __restrict__ Wbf,
    const float* __restrict__ x, const float* __restrict__ h,
    const float* __restrict__ wii, const float* __restrict__ wif,
    const float* __restrict__ wig, const float* __restrict__ wio,
    const float* __restrict__ whi, const float* __restrict__ whf,
    const float* __restrict__ whg, const float* __restrict__ who,
    const float* __restrict__ c_in,
    const float* __restrict__ bias_i, const float* __restrict__ bias_f,
    const float* __restrict__ bias_g, const float* __restrict__ bias_o,
    float* __restrict__ out) {
  __shared__ unsigned short Ald[BM * BK];   // 16 KB, row-major [128][64], swizzled
  __shared__ unsigned short Bld[128 * BK];  // 16 KB, row rb = gate*32+jj, swizzled

  int tid = threadIdx.x;
  int lane = tid & 63;
  int wid = tid >> 6;
  int wr = wid >> 1, wc = wid & 1;

  int bid = blockIdx.x;                    // 2048 blocks
  int swz = (bid & 7) * 256 + (bid >> 3);  // bijective XCD swizzle (2048 = 8*256)
  int mt = swz & 31;                       // 32 M-tiles; consecutive swz share ht -> W panel L2-hot
  int ht = swz >> 5;                       // 64 H-tiles
  int m0 = mt * BM;
  int j0 = ht * BH;

  f32x4 acc[4][4];
  #pragma unroll
  for (int a = 0; a < 4; a++)
    #pragma unroll
    for (int b = 0; b < 4; b++) acc[a][b] = (f32x4){0.f, 0.f, 0.f, 0.f};

  int lrow = lane & 15;
  int lsw = lrow & 7;                      // swizzle key for reads
  int qbase = lane >> 4;                   // 16B-chunk group within 64B half

  for (int kt = 0; kt < NKT; kt++) {
    int k0 = kt * BK;
    if (MODE == 0) {
      #pragma unroll
      for (int i = 0; i < 4; i++) {
        int c = i * 256 + tid;
        int r = c >> 3, cc = c & 7;
        int ccs = cc ^ (r & 7);            // inverse-swizzled SOURCE chunk
        gload_lds16(Abf + (size_t)(m0 + r) * 4096 + k0 + ccs * 8,
                    (char*)Ald + (size_t)c * 16);
      }
      #pragma unroll
      for (int i = 0; i < 4; i++) {
        int c = i * 256 + tid;
        int rb = c >> 3, cc = c & 7;
        int ccs = cc ^ (rb & 7);
        int wrow = (rb >> 5) * 2048 + j0 + (rb & 31);
        gload_lds16(Wbf + (size_t)wrow * 4096 + k0 + ccs * 8,
                    (char*)Bld + (size_t)c * 16);
      }
    } else {
      // fallback: reg-staged fp32 load + convert + ds_write (no workspace needed)
      const float* Asrc = (k0 < 2048) ? x : h;
      int ka = k0 & 2047;
      #pragma unroll
      for (int i = 0; i < 4; i++) {
        int c = i * 256 + tid;
        int r = c >> 3, cc = c & 7;
        int ccs = cc ^ (r & 7);
        const float* s = Asrc + (size_t)(m0 + r) * 2048 + ka + ccs * 8;
        float4 v0 = *(const float4*)s;
        float4 v1 = *(const float4*)(s + 4);
        bf16x8 pk;
        pk[0] = (short)f2bf(v0.x); pk[1] = (short)f2bf(v0.y);
        pk[2] = (short)f2bf(v0.z); pk[3] = (short)f2bf(v0.w);
        pk[4] = (short)f2bf(v1.x); pk[5] = (short)f2bf(v1.y);
        pk[6] = (short)f2bf(v1.z); pk[7] = (short)f2bf(v1.w);
        *(bf16x8*)((char*)Ald + (size_t)c * 16) = pk;
      }
      #pragma unroll
      for (int i = 0; i < 4; i++) {
        int c = i * 256 + tid;
        int rb = c >> 3, cc = c & 7;
        int ccs = cc ^ (rb & 7);
        int g = rb >> 5, jj = rb & 31;
        const float* Bsrc;
        if (k0 < 2048) Bsrc = (g == 0) ? wii : (g == 1) ? wif : (g == 2) ? wig : wio;
        else           Bsrc = (g == 0) ? whi : (g == 1) ? whf : (g == 2) ? whg : who;
        const float* s = Bsrc + (size_t)(j0 + jj) * 2048 + ka + ccs * 8;
        float4 v0 = *(const float4*)s;
        float4 v1 = *(const float4*)(s + 4);
        bf16x8 pk;
        pk[0] = (short)f2bf(v0.x); pk[1] = (short)f2bf(v0.y);
        pk[2] = (short)f2bf(v0.z); pk[3] = (short)f2bf(v0.w);
        pk[4] = (short)f2bf(v1.x); pk[5] = (short)f2bf(v1.y);
        pk[6] = (short)f2bf(v1.z); pk[7] = (short)f2bf(v1.w);
        *(bf16x8*)((char*)Bld + (size_t)c * 16) = pk;
      }
    }
    __syncthreads();   // drains vmcnt (global_load_lds) / lgkm (ds_write)

    #pragma unroll
    for (int ks = 0; ks < 2; ks++) {
      int q = ks * 4 + qbase;              // logical 16B chunk 0..7 within row
      int qs8 = (q ^ lsw) * 8;             // swizzled element offset
      bf16x8 af[4], bg[4];
      #pragma unroll
      for (int mf = 0; mf < 4; mf++)
        af[mf] = *(const bf16x8*)&Ald[(wr * 64 + mf * 16 + lrow) * 64 + qs8];
      #pragma unroll
      for (int g = 0; g < 4; g++)
        bg[g] = *(const bf16x8*)&Bld[(g * 32 + wc * 16 + lrow) * 64 + qs8];
      #pragma unroll
      for (int mf = 0; mf < 4; mf++)
        #pragma unroll
        for (int g = 0; g < 4; g++)
          acc[mf][g] = __builtin_amdgcn_mfma_f32_16x16x32_bf16(af[mf], bg[g], acc[mf][g], 0, 0, 0);
    }
    __syncthreads();   // protect LDS before next stage overwrites
  }

  // ---- epilogue: all 4 gates for (m, j) are thread-local
  int j = j0 + wc * 16 + lrow;
  float bi = bias_i[j], bff = bias_f[j], bgg = bias_g[j], bo = bias_o[j];
  int rbase = m0 + wr * 64 + (lane >> 4) * 4;
  #pragma unroll
  for (int mf = 0; mf < 4; mf++) {
    #pragma unroll
    for (int q = 0; q < 4; q++) {
      int m = rbase + mf * 16 + q;          // C/D layout: col=lane&15, row=(lane>>4)*4+q
      size_t off = (size_t)m * HID + j;
      float gi = acc[mf][0][q] + bi;
      float gf = acc[mf][1][q] + bff;
      float gg = acc[mf][2][q] + bgg;
      float go = acc[mf][3][q] + bo;
      float iv = 1.f / (1.f + __expf(-gi));
      float fv = 1.f / (1.f + __expf(-gf));
      float gv = tanhf(gg);
      float ov = 1.f / (1.f + __expf(-go));
      float cn = fv * c_in[off] + iv * gv;
      float hn = ov * tanhf(cn);
      out[off] = hn;                                 // h_new
      out[(size_t)BATCH * HID + off] = cn;           // c_new
    }
  }
}

extern "C" void kernel_launch(void* const* d_in, const int* in_sizes, int n_in,
                              void* d_out, int out_size, void* d_ws, size_t ws_size,
                              hipStream_t stream) {
  const float* x   = (const float*)d_in[0];
  const float* h   = (const float*)d_in[1];
  const float* c   = (const float*)d_in[2];
  const float* wii = (const float*)d_in[3];
  const float* wif = (const float*)d_in[4];
  const float* wig = (const float*)d_in[5];
  const float* wio = (const float*)d_in[6];
  const float* whi = (const float*)d_in[7];
  const float* whf = (const float*)d_in[8];
  const float* whg = (const float*)d_in[9];
  const float* who = (const float*)d_in[10];
  const float* bi  = (const float*)d_in[11];
  const float* bf  = (const float*)d_in[12];
  const float* bg  = (const float*)d_in[13];
  const float* bo  = (const float*)d_in[14];
  float* out = (float*)d_out;

  size_t needA = (size_t)4096 * 4096 * 2;   // 32 MB bf16
  size_t needW = (size_t)8192 * 4096 * 2;   // 64 MB bf16

  if (ws_size >= needA + needW) {
    unsigned short* Abf = (unsigned short*)d_ws;
    unsigned short* Wbf = (unsigned short*)((char*)d_ws + needA);
    convert_kernel<<<dim3(4096, 12), 256, 0, stream>>>(
        x, h, wii, wif, wig, wio, whi, whf, whg, who, Abf, Wbf);
    lstm_gemm<0><<<2048, 256, 0, stream>>>(
        Abf, Wbf, x, h, wii, wif, wig, wio, whi, whf, whg, who,
        c, bi, bf, bg, bo, out);
  } else {
    lstm_gemm<1><<<2048, 256, 0, stream>>>(
        nullptr, nullptr, x, h, wii, wif, wig, wio, whi, whf, whg, who,
        c, bi, bf, bg, bo, out);
  }
}

// Round 4
// 328.622 us; speedup vs baseline: 1.4591x; 1.2582x over previous
//
#include <hip/hip_runtime.h>
#include <cstdint>
#include <cstddef>

#define BATCH 4096
#define HID   2048
#define KTOT  4096
#define NT    64          // K-tiles of 64

typedef __attribute__((ext_vector_type(8))) short bf16x8;
typedef __attribute__((ext_vector_type(4))) float f32x4;

__device__ __forceinline__ unsigned short f2bf(float f) {
  union { float f; unsigned u; } a; a.f = f;
  unsigned u = a.u;
  return (unsigned short)((u + 0x7FFFu + ((u >> 16) & 1u)) >> 16);  // RNE
}

__device__ __forceinline__ void gload_lds16(const void* g, void* l) {
  __builtin_amdgcn_global_load_lds((const __attribute__((address_space(1))) void*)g,
                                   (__attribute__((address_space(3))) void*)l, 16, 0, 0);
}

#define SBAR() do { __builtin_amdgcn_sched_barrier(0); __builtin_amdgcn_s_barrier(); \
                    __builtin_amdgcn_sched_barrier(0); } while (0)
#define VMCNT4() do { __builtin_amdgcn_sched_barrier(0); \
                      asm volatile("s_waitcnt vmcnt(4)" ::: "memory"); } while (0)
#define VMCNT0() do { __builtin_amdgcn_sched_barrier(0); \
                      asm volatile("s_waitcnt vmcnt(0)" ::: "memory"); } while (0)

// ---- fp32 -> bf16 pack (verified r1): A=[x|h] 4096x4096; Wbf gate-major 8192x4096
__global__ __launch_bounds__(256) void convert_kernel(
    const float* __restrict__ x, const float* __restrict__ h,
    const float* __restrict__ wii, const float* __restrict__ wif,
    const float* __restrict__ wig, const float* __restrict__ wio,
    const float* __restrict__ whi, const float* __restrict__ whf,
    const float* __restrict__ whg, const float* __restrict__ who,
    unsigned short* __restrict__ Abf, unsigned short* __restrict__ Wbf) {
  int seg = blockIdx.y;
  const float* src;
  unsigned short* dst;
  int ofs;
  size_t rofs;
  if (seg < 4) {
    src = (seg < 2) ? x : h;
    dst = Abf;
    ofs = (seg < 2) ? 0 : 2048;
    rofs = (seg & 1) ? 2048 : 0;
    src += rofs * 2048;
  } else {
    int g = (seg - 4) & 3;
    dst = Wbf + (size_t)g * 2048 * 4096;
    ofs = (seg >= 8) ? 2048 : 0;
    rofs = 0;
    switch (seg) {
      case 4: src = wii; break; case 5: src = wif; break;
      case 6: src = wig; break; case 7: src = wio; break;
      case 8: src = whi; break; case 9: src = whf; break;
      case 10: src = whg; break; default: src = who; break;
    }
  }
  size_t idx = (size_t)blockIdx.x * 256 + threadIdx.x;
  size_t e = idx * 4;
  int n = (int)(e >> 11);
  int k = (int)(e & 2047);
  float4 v = *(const float4*)(src + e);
  ushort4 o;
  o.x = f2bf(v.x); o.y = f2bf(v.y); o.z = f2bf(v.z); o.w = f2bf(v.w);
  *(ushort4*)(dst + (rofs + (size_t)n) * 4096 + ofs + k) = o;
}

// ---- staging: one 16KB part (256 rows x 32 bf16), linear LDS dest,
// inverse-swizzled global source chunk (T2, both-sides rule #21).
__device__ __forceinline__ void stage_A(const unsigned short* __restrict__ Abf,
                                        unsigned short* dst, int m0, int kc, int tid) {
  #pragma unroll
  for (int i = 0; i < 2; i++) {
    int c = i * 512 + tid;                 // 0..1023 16B-chunks
    int r = c >> 2, cc = c & 3;
    int ccs = cc ^ ((r >> 1) & 3);
    gload_lds16(Abf + (size_t)(m0 + r) * 4096 + kc + ccs * 8,
                (char*)dst + (size_t)c * 16);
  }
}
// B rows: packed p_local = r -> gate g=(r>>4)&3, j = bn*64 + ((r>>6)&3)*16 + (r&15)
__device__ __forceinline__ void stage_B(const unsigned short* __restrict__ Wbf,
                                        unsigned short* dst, int bn, int kc, int tid) {
  #pragma unroll
  for (int i = 0; i < 2; i++) {
    int c = i * 512 + tid;
    int r = c >> 2, cc = c & 3;
    int ccs = cc ^ ((r >> 1) & 3);
    int g = (r >> 4) & 3;
    int j = bn * 64 + ((r >> 6) & 3) * 16 + (r & 15);
    gload_lds16(Wbf + ((size_t)g * 2048 + j) * 4096 + kc + ccs * 8,
                (char*)dst + (size_t)c * 16);
  }
}

__device__ __forceinline__ bf16x8 ldfrag(const unsigned short* part, int row, int qh) {
  return *(const bf16x8*)(part + row * 32 + ((qh ^ ((row >> 1) & 3)) << 3));
}

// ---- 256x256-tile 8-phase LSTM GEMM (T2+T3+T4+T5), gates = A @ Wcat^T + epilogue
__global__ __launch_bounds__(512, 2) void lstm_gemm8(
    const unsigned short* __restrict__ Abf, const unsigned short* __restrict__ Wbf,
    const float* __restrict__ c_in,
    const float* __restrict__ bias_i, const float* __restrict__ bias_f,
    const float* __restrict__ bias_g, const float* __restrict__ bias_o,
    float* __restrict__ out) {
  // 2 dbuf x 4 parts (A0,B0,A1,B1; K-split k0-31 / k32-63) x 16KB = 128KB
  __shared__ unsigned short lds[2][4][256 * 32];

  int tid = threadIdx.x;
  int lane = tid & 63;
  int wid = tid >> 6;            // 0..7
  int wr = wid >> 2;             // 0..1  M-half (128 rows)
  int wc = wid & 3;              // 0..3  N-quarter (64 packed rows)
  int lrow = lane & 15;
  int qh = lane >> 4;            // 0..3 16B chunk within 32-k slice

  int bid = blockIdx.x;          // 512 blocks = 16 mt x 32 bn
  int xcd = bid & 7;
  int t7 = bid >> 3;             // 0..63
  int mt = t7 & 15;
  int bn = xcd * 4 + (t7 >> 4);  // each XCD owns 4 bn columns (W panel L2-hot)
  int m0 = mt * 256;

  f32x4 acc[8][4];
  #pragma unroll
  for (int a = 0; a < 8; a++)
    #pragma unroll
    for (int b = 0; b < 4; b++) acc[a][b] = (f32x4){0.f, 0.f, 0.f, 0.f};

  int arow0 = wr * 128 + lrow;   // A frag row base (part-local)
  int brow0 = wc * 64 + lrow;    // B frag row base (part-local)

  // ---- prologue: stage tile 0 fully; drain A0,B0 (leave A1,B1 in flight)
  stage_A(Abf, lds[0][0], m0, 0, tid);
  stage_B(Wbf, lds[0][1], bn, 0, tid);
  stage_A(Abf, lds[0][2], m0, 32, tid);
  stage_B(Wbf, lds[0][3], bn, 32, tid);
  VMCNT4();
  SBAR();

  // ---- main loop: tiles 0..NT-2, staging tile t+1 (1 part per phase)
  for (int t = 0; t < NT - 1; ++t) {
    int b = t & 1;
    const unsigned short* A0 = lds[b][0];
    const unsigned short* B0 = lds[b][1];
    const unsigned short* A1 = lds[b][2];
    const unsigned short* B1 = lds[b][3];
    unsigned short* nA0 = lds[b ^ 1][0];
    unsigned short* nB0 = lds[b ^ 1][1];
    unsigned short* nA1 = lds[b ^ 1][2];
    unsigned short* nB1 = lds[b ^ 1][3];
    int k1 = (t + 1) * 64;

    bf16x8 afr[4], bfr[4];
    // -- phase a: kk0, M-half0 (reads 8) ; stage t+1.A0
    #pragma unroll
    for (int m = 0; m < 4; m++) afr[m] = ldfrag(A0, arow0 + m * 16, qh);
    #pragma unroll
    for (int n = 0; n < 4; n++) bfr[n] = ldfrag(B0, brow0 + n * 16, qh);
    stage_A(Abf, nA0, m0, k1, tid);
    SBAR();
    __builtin_amdgcn_s_setprio(1);
    #pragma unroll
    for (int m = 0; m < 4; m++)
      #pragma unroll
      for (int n = 0; n < 4; n++)
        acc[m][n] = __builtin_amdgcn_mfma_f32_16x16x32_bf16(afr[m], bfr[n], acc[m][n], 0, 0, 0);
    __builtin_amdgcn_s_setprio(0);
    SBAR();
    // -- phase b: kk0, M-half1 (reads 4) ; stage t+1.B0 ; wait covers THIS tile's A1,B1
    #pragma unroll
    for (int m = 0; m < 4; m++) afr[m] = ldfrag(A0, arow0 + 64 + m * 16, qh);
    stage_B(Wbf, nB0, bn, k1, tid);
    SBAR();
    __builtin_amdgcn_s_setprio(1);
    #pragma unroll
    for (int m = 0; m < 4; m++)
      #pragma unroll
      for (int n = 0; n < 4; n++)
        acc[4 + m][n] = __builtin_amdgcn_mfma_f32_16x16x32_bf16(afr[m], bfr[n], acc[4 + m][n], 0, 0, 0);
    __builtin_amdgcn_s_setprio(0);
    VMCNT4();
    SBAR();
    // -- phase c: kk1, M-half0 (reads 8) ; stage t+1.A1
    #pragma unroll
    for (int m = 0; m < 4; m++) afr[m] = ldfrag(A1, arow0 + m * 16, qh);
    #pragma unroll
    for (int n = 0; n < 4; n++) bfr[n] = ldfrag(B1, brow0 + n * 16, qh);
    stage_A(Abf, nA1, m0, k1 + 32, tid);
    SBAR();
    __builtin_amdgcn_s_setprio(1);
    #pragma unroll
    for (int m = 0; m < 4; m++)
      #pragma unroll
      for (int n = 0; n < 4; n++)
        acc[m][n] = __builtin_amdgcn_mfma_f32_16x16x32_bf16(afr[m], bfr[n], acc[m][n], 0, 0, 0);
    __builtin_amdgcn_s_setprio(0);
    SBAR();
    // -- phase d: kk1, M-half1 (reads 4) ; stage t+1.B1 ; wait covers NEXT tile's A0,B0
    #pragma unroll
    for (int m = 0; m < 4; m++) afr[m] = ldfrag(A1, arow0 + 64 + m * 16, qh);
    stage_B(Wbf, nB1, bn, k1 + 32, tid);
    SBAR();
    __builtin_amdgcn_s_setprio(1);
    #pragma unroll
    for (int m = 0; m < 4; m++)
      #pragma unroll
      for (int n = 0; n < 4; n++)
        acc[4 + m][n] = __builtin_amdgcn_mfma_f32_16x16x32_bf16(afr[m], bfr[n], acc[4 + m][n], 0, 0, 0);
    __builtin_amdgcn_s_setprio(0);
    VMCNT4();
    SBAR();
  }

  // ---- peeled last tile (t = NT-1, buffer 1): no staging; drain at end of phase b
  {
    const unsigned short* A0 = lds[1][0];
    const unsigned short* B0 = lds[1][1];
    const unsigned short* A1 = lds[1][2];
    const unsigned short* B1 = lds[1][3];
    bf16x8 afr[4], bfr[4];
    #pragma unroll
    for (int m = 0; m < 4; m++) afr[m] = ldfrag(A0, arow0 + m * 16, qh);
    #pragma unroll
    for (int n = 0; n < 4; n++) bfr[n] = ldfrag(B0, brow0 + n * 16, qh);
    SBAR();
    #pragma unroll
    for (int m = 0; m < 4; m++)
      #pragma unroll
      for (int n = 0; n < 4; n++)
        acc[m][n] = __builtin_amdgcn_mfma_f32_16x16x32_bf16(afr[m], bfr[n], acc[m][n], 0, 0, 0);
    SBAR();
    #pragma unroll
    for (int m = 0; m < 4; m++) afr[m] = ldfrag(A0, arow0 + 64 + m * 16, qh);
    SBAR();
    #pragma unroll
    for (int m = 0; m < 4; m++)
      #pragma unroll
      for (int n = 0; n < 4; n++)
        acc[4 + m][n] = __builtin_amdgcn_mfma_f32_16x16x32_bf16(afr[m], bfr[n], acc[4 + m][n], 0, 0, 0);
    VMCNT0();   // last tile's A1,B1 (staged during t=NT-2) must land
    SBAR();
    #pragma unroll
    for (int m = 0; m < 4; m++) afr[m] = ldfrag(A1, arow0 + m * 16, qh);
    #pragma unroll
    for (int n = 0; n < 4; n++) bfr[n] = ldfrag(B1, brow0 + n * 16, qh);
    SBAR();
    #pragma unroll
    for (int m = 0; m < 4; m++)
      #pragma unroll
      for (int n = 0; n < 4; n++)
        acc[m][n] = __builtin_amdgcn_mfma_f32_16x16x32_bf16(afr[m], bfr[n], acc[m][n], 0, 0, 0);
    SBAR();
    #pragma unroll
    for (int m = 0; m < 4; m++) afr[m] = ldfrag(A1, arow0 + 64 + m * 16, qh);
    #pragma unroll
    for (int m = 0; m < 4; m++)
      #pragma unroll
      for (int n = 0; n < 4; n++)
        acc[4 + m][n] = __builtin_amdgcn_mfma_f32_16x16x32_bf16(afr[m], bfr[n], acc[4 + m][n], 0, 0, 0);
  }

  // ---- epilogue: gates thread-local across n (n == gate index)
  int j = bn * 64 + wc * 16 + lrow;
  float bi = bias_i[j], bff = bias_f[j], bgg = bias_g[j], bo = bias_o[j];
  int rbase = m0 + wr * 128 + qh * 4;
  #pragma unroll
  for (int mf = 0; mf < 8; mf++) {
    #pragma unroll
    for (int qq = 0; qq < 4; qq++) {
      int m = rbase + mf * 16 + qq;       // C/D: col=lane&15, row=(lane>>4)*4+qq
      size_t off = (size_t)m * HID + j;
      float gi = acc[mf][0][qq] + bi;
      float gf = acc[mf][1][qq] + bff;
      float gg = acc[mf][2][qq] + bgg;
      float go = acc[mf][3][qq] + bo;
      float iv = 1.f / (1.f + __expf(-gi));
      float fv = 1.f / (1.f + __expf(-gf));
      float gv = tanhf(gg);
      float ov = 1.f / (1.f + __expf(-go));
      float cn = fv * c_in[off] + iv * gv;
      float hn = ov * tanhf(cn);
      out[off] = hn;
      out[(size_t)BATCH * HID + off] = cn;
    }
  }
}

// ---- fallback (no workspace): round-3 verified 128-tile reg-staged kernel
__global__ __launch_bounds__(256) void lstm_gemm_fb(
    const float* __restrict__ x, const float* __restrict__ h,
    const float* __restrict__ wii, const float* __restrict__ wif,
    const float* __restrict__ wig, const float* __restrict__ wio,
    const float* __restrict__ whi, const float* __restrict__ whf,
    const float* __restrict__ whg, const float* __restrict__ who,
    const float* __restrict__ c_in,
    const float* __restrict__ bias_i, const float* __restrict__ bias_f,
    const float* __restrict__ bias_g, const float* __restrict__ bias_o,
    float* __restrict__ out) {
  __shared__ unsigned short Ald[128 * 64];
  __shared__ unsigned short Bld[128 * 64];
  int tid = threadIdx.x;
  int lane = tid & 63;
  int wid = tid >> 6;
  int wr = wid >> 1, wc = wid & 1;
  int bid = blockIdx.x;
  int swz = (bid & 7) * 256 + (bid >> 3);
  int mt = swz & 31;
  int ht = swz >> 5;
  int m0 = mt * 128;
  int j0 = ht * 32;
  f32x4 acc[4][4];
  #pragma unroll
  for (int a = 0; a < 4; a++)
    #pragma unroll
    for (int b = 0; b < 4; b++) acc[a][b] = (f32x4){0.f, 0.f, 0.f, 0.f};
  int lrow = lane & 15;
  int lsw = lrow & 7;
  int qbase = lane >> 4;
  for (int kt = 0; kt < 64; kt++) {
    int k0 = kt * 64;
    const float* Asrc = (k0 < 2048) ? x : h;
    int ka = k0 & 2047;
    #pragma unroll
    for (int i = 0; i < 4; i++) {
      int c = i * 256 + tid;
      int r = c >> 3, cc = c & 7;
      int ccs = cc ^ (r & 7);
      const float* s = Asrc + (size_t)(m0 + r) * 2048 + ka + ccs * 8;
      float4 v0 = *(const float4*)s;
      float4 v1 = *(const float4*)(s + 4);
      bf16x8 pk;
      pk[0] = (short)f2bf(v0.x); pk[1] = (short)f2bf(v0.y);
      pk[2] = (short)f2bf(v0.z); pk[3] = (short)f2bf(v0.w);
      pk[4] = (short)f2bf(v1.x); pk[5] = (short)f2bf(v1.y);
      pk[6] = (short)f2bf(v1.z); pk[7] = (short)f2bf(v1.w);
      *(bf16x8*)((char*)Ald + (size_t)c * 16) = pk;
    }
    #pragma unroll
    for (int i = 0; i < 4; i++) {
      int c = i * 256 + tid;
      int rb = c >> 3, cc = c & 7;
      int ccs = cc ^ (rb & 7);
      int g = rb >> 5, jj = rb & 31;
      const float* Bsrc;
      if (k0 < 2048) Bsrc = (g == 0) ? wii : (g == 1) ? wif : (g == 2) ? wig : wio;
      else           Bsrc = (g == 0) ? whi : (g == 1) ? whf : (g == 2) ? whg : who;
      const float* s = Bsrc + (size_t)(j0 + jj) * 2048 + ka + ccs * 8;
      float4 v0 = *(const float4*)s;
      float4 v1 = *(const float4*)(s + 4);
      bf16x8 pk;
      pk[0] = (short)f2bf(v0.x); pk[1] = (short)f2bf(v0.y);
      pk[2] = (short)f2bf(v0.z); pk[3] = (short)f2bf(v0.w);
      pk[4] = (short)f2bf(v1.x); pk[5] = (short)f2bf(v1.y);
      pk[6] = (short)f2bf(v1.z); pk[7] = (short)f2bf(v1.w);
      *(bf16x8*)((char*)Bld + (size_t)c * 16) = pk;
    }
    __syncthreads();
    #pragma unroll
    for (int ks = 0; ks < 2; ks++) {
      int q = ks * 4 + qbase;
      int qs8 = (q ^ lsw) * 8;
      bf16x8 af[4], bg[4];
      #pragma unroll
      for (int mf = 0; mf < 4; mf++)
        af[mf] = *(const bf16x8*)&Ald[(wr * 64 + mf * 16 + lrow) * 64 + qs8];
      #pragma unroll
      for (int g = 0; g < 4; g++)
        bg[g] = *(const bf16x8*)&Bld[(g * 32 + wc * 16 + lrow) * 64 + qs8];
      #pragma unroll
      for (int mf = 0; mf < 4; mf++)
        #pragma unroll
        for (int g = 0; g < 4; g++)
          acc[mf][g] = __builtin_amdgcn_mfma_f32_16x16x32_bf16(af[mf], bg[g], acc[mf][g], 0, 0, 0);
    }
    __syncthreads();
  }
  int j = j0 + wc * 16 + lrow;
  float bi = bias_i[j], bff = bias_f[j], bgg = bias_g[j], bo = bias_o[j];
  int rbase = m0 + wr * 64 + (lane >> 4) * 4;
  #pragma unroll
  for (int mf = 0; mf < 4; mf++) {
    #pragma unroll
    for (int q = 0; q < 4; q++) {
      int m = rbase + mf * 16 + q;
      size_t off = (size_t)m * HID + j;
      float gi = acc[mf][0][q] + bi;
      float gf = acc[mf][1][q] + bff;
      float gg = acc[mf][2][q] + bgg;
      float go = acc[mf][3][q] + bo;
      float iv = 1.f / (1.f + __expf(-gi));
      float fv = 1.f / (1.f + __expf(-gf));
      float gv = tanhf(gg);
      float ov = 1.f / (1.f + __expf(-go));
      float cn = fv * c_in[off] + iv * gv;
      float hn = ov * tanhf(cn);
      out[off] = hn;
      out[(size_t)BATCH * HID + off] = cn;
    }
  }
}

extern "C" void kernel_launch(void* const* d_in, const int* in_sizes, int n_in,
                              void* d_out, int out_size, void* d_ws, size_t ws_size,
                              hipStream_t stream) {
  const float* x   = (const float*)d_in[0];
  const float* h   = (const float*)d_in[1];
  const float* c   = (const float*)d_in[2];
  const float* wii = (const float*)d_in[3];
  const float* wif = (const float*)d_in[4];
  const float* wig = (const float*)d_in[5];
  const float* wio = (const float*)d_in[6];
  const float* whi = (const float*)d_in[7];
  const float* whf = (const float*)d_in[8];
  const float* whg = (const float*)d_in[9];
  const float* who = (const float*)d_in[10];
  const float* bi  = (const float*)d_in[11];
  const float* bf  = (const float*)d_in[12];
  const float* bg  = (const float*)d_in[13];
  const float* bo  = (const float*)d_in[14];
  float* out = (float*)d_out;

  size_t needA = (size_t)4096 * 4096 * 2;
  size_t needW = (size_t)8192 * 4096 * 2;

  if (ws_size >= needA + needW) {
    unsigned short* Abf = (unsigned short*)d_ws;
    unsigned short* Wbf = (unsigned short*)((char*)d_ws + needA);
    convert_kernel<<<dim3(4096, 12), 256, 0, stream>>>(
        x, h, wii, wif, wig, wio, whi, whf, whg, who, Abf, Wbf);
    lstm_gemm8<<<512, 512, 0, stream>>>(Abf, Wbf, c, bi, bf, bg, bo, out);
  } else {
    lstm_gemm_fb<<<2048, 256, 0, stream>>>(
        x, h, wii, wif, wig, wio, whi, whf, whg, who,
        c, bi, bf, bg, bo, out);
  }
}

// Round 5
// 317.314 us; speedup vs baseline: 1.5111x; 1.0356x over previous
//
#include <hip/hip_runtime.h>
#include <cstdint>
#include <cstddef>

#define BATCH 4096
#define HID   2048
#define NT    64          // K-tiles of 64

typedef __attribute__((ext_vector_type(8))) short bf16x8;
typedef __attribute__((ext_vector_type(4))) float f32x4;

__device__ __forceinline__ unsigned short f2bf(float f) {
  union { float f; unsigned u; } a; a.f = f;
  unsigned u = a.u;
  return (unsigned short)((u + 0x7FFFu + ((u >> 16) & 1u)) >> 16);  // RNE
}

__device__ __forceinline__ void gload_lds16(const void* g, void* l) {
  __builtin_amdgcn_global_load_lds((const __attribute__((address_space(1))) void*)g,
                                   (__attribute__((address_space(3))) void*)l, 16, 0, 0);
}

#define SCHED0() __builtin_amdgcn_sched_barrier(0)
#define SBAR()  do { SCHED0(); __builtin_amdgcn_s_barrier(); SCHED0(); } while (0)
#define WAITV(N) do { SCHED0(); asm volatile("s_waitcnt vmcnt(" #N ")" ::: "memory"); SCHED0(); } while (0)
#define WAITL(N) do { SCHED0(); asm volatile("s_waitcnt lgkmcnt(" #N ")" ::: "memory"); SCHED0(); } while (0)
#define DSR_(dst, adr, S) asm volatile("ds_read_b128 %0, %1 offset:" S : "=v"(dst) : "v"(adr))
#define DSR(dst, adr, IMM) DSR_(dst, adr, #IMM)

// issue 12 ds_read_b128 for one K-slice: A rows (8 frags) + B rows (4 frags)
#define READ_CLUSTER(AADR, BADR) do { \
  DSR(a1[0], (AADR), 0); DSR(a1[1], (AADR), 1024); DSR(a1[2], (AADR), 2048); DSR(a1[3], (AADR), 3072); \
  DSR(bf_[0], (BADR), 0); DSR(bf_[1], (BADR), 1024); DSR(bf_[2], (BADR), 2048); DSR(bf_[3], (BADR), 3072); \
  DSR(a2[0], (AADR), 4096); DSR(a2[1], (AADR), 5120); DSR(a2[2], (AADR), 6144); DSR(a2[3], (AADR), 7168); \
} while (0)

#define MFMA_HALF(AF, OFS) do { \
  _Pragma("unroll") \
  for (int m_ = 0; m_ < 4; m_++) { \
    _Pragma("unroll") \
    for (int n_ = 0; n_ < 4; n_++) \
      acc[(OFS) + m_][n_] = __builtin_amdgcn_mfma_f32_16x16x32_bf16(AF[m_], bf_[n_], acc[(OFS) + m_][n_], 0, 0, 0); \
  } \
} while (0)

// ---- fp32 -> bf16 pack (verified r2): A=[x|h] 4096x4096; Wbf gate-major 8192x4096
__global__ __launch_bounds__(256) void convert_kernel(
    const float* __restrict__ x, const float* __restrict__ h,
    const float* __restrict__ wii, const float* __restrict__ wif,
    const float* __restrict__ wig, const float* __restrict__ wio,
    const float* __restrict__ whi, const float* __restrict__ whf,
    const float* __restrict__ whg, const float* __restrict__ who,
    unsigned short* __restrict__ Abf, unsigned short* __restrict__ Wbf) {
  int seg = blockIdx.y;
  const float* src;
  unsigned short* dst;
  int ofs;
  size_t rofs;
  if (seg < 4) {
    src = (seg < 2) ? x : h;
    dst = Abf;
    ofs = (seg < 2) ? 0 : 2048;
    rofs = (seg & 1) ? 2048 : 0;
    src += rofs * 2048;
  } else {
    int g = (seg - 4) & 3;
    dst = Wbf + (size_t)g * 2048 * 4096;
    ofs = (seg >= 8) ? 2048 : 0;
    rofs = 0;
    switch (seg) {
      case 4: src = wii; break; case 5: src = wif; break;
      case 6: src = wig; break; case 7: src = wio; break;
      case 8: src = whi; break; case 9: src = whf; break;
      case 10: src = whg; break; default: src = who; break;
    }
  }
  size_t idx = (size_t)blockIdx.x * 256 + threadIdx.x;
  size_t e = idx * 4;
  int n = (int)(e >> 11);
  int k = (int)(e & 2047);
  float4 v = *(const float4*)(src + e);
  ushort4 o;
  o.x = f2bf(v.x); o.y = f2bf(v.y); o.z = f2bf(v.z); o.w = f2bf(v.w);
  *(ushort4*)(dst + (rofs + (size_t)n) * 4096 + ofs + k) = o;
}

// ---- 256x256-tile LSTM GEMM, asm ds_read + counted waits (T2+T3+T4+T5)
// 2 barriers + 2x vmcnt(4) per K-tile; reads from buf b, stages into buf b^1.
__global__ __launch_bounds__(512, 2) void lstm_gemm8(
    const unsigned short* __restrict__ Abf, const unsigned short* __restrict__ Wbf,
    const float* __restrict__ c_in,
    const float* __restrict__ bias_i, const float* __restrict__ bias_f,
    const float* __restrict__ bias_g, const float* __restrict__ bias_o,
    float* __restrict__ out) {
  // 2 dbuf x 4 parts (A0,B0,A1,B1; K-split 0-31 / 32-63) x 16KB = 128KB
  __shared__ unsigned short lds[2][4][256 * 32];

  int tid = threadIdx.x;
  int lane = tid & 63;
  int wid = tid >> 6;            // 0..7
  int wr = wid >> 2;             // M-half (128 rows)
  int wc = wid & 3;              // N-quarter (64 packed rows)
  int lrow = lane & 15;
  int qh = lane >> 4;            // 16B chunk within 32-k part

  int bid = blockIdx.x;          // 512 blocks = 16 mt x 32 bn
  int xcd = bid & 7;
  int t7 = bid >> 3;
  int mt = t7 & 15;
  int bn = xcd * 4 + (t7 >> 4);  // each XCD owns 4 bn columns
  int m0 = mt * 256;

  // ---- precomputed staging source addresses (strides verified:
  // i=1 load: A row +128 -> +128*4096 elem; B row +32 -> +32*4096; swizzle key invariant)
  int r0 = tid >> 2, cc0 = tid & 3;
  int ccs0 = cc0 ^ ((r0 >> 1) & 3);
  const unsigned short* pA = Abf + (size_t)(m0 + r0) * 4096 + ccs0 * 8;
  int g0 = (r0 >> 4) & 3;
  int jw = bn * 64 + ((r0 >> 6) & 3) * 16 + (r0 & 15);
  const unsigned short* pB = Wbf + ((size_t)g0 * 2048 + jw) * 4096 + ccs0 * 8;

  char* L0 = (char*)&lds[0][0][0];
  char* dA = L0 + tid * 16;      // linear LDS dest; +buf*65536 +part*16384 (+8192 i=1)
  unsigned ldsOff = (unsigned)(size_t)(__attribute__((address_space(3))) char*)L0;

  int arow0 = wr * 128 + lrow;
  int brow0 = wc * 64 + lrow;
  unsigned qsA = ((unsigned)(qh ^ ((arow0 >> 1) & 3))) << 4;   // swizzled 16B chunk (bytes)
  unsigned qsB = ((unsigned)(qh ^ ((brow0 >> 1) & 3))) << 4;
  unsigned aB0 = ldsOff + (unsigned)arow0 * 64 + qsA;           // buf0 part0
  unsigned bB0 = ldsOff + 16384u + (unsigned)brow0 * 64 + qsB;  // buf0 part1

  f32x4 acc[8][4];
  #pragma unroll
  for (int a = 0; a < 8; a++)
    #pragma unroll
    for (int b = 0; b < 4; b++) acc[a][b] = (f32x4){0.f, 0.f, 0.f, 0.f};

  // ---- prologue: stage tile 0 (A0,B0 oldest so vmcnt(4) drains exactly them)
  gload_lds16(pA, dA);
  gload_lds16(pA + 128 * 4096, dA + 8192);
  gload_lds16(pB, dA + 16384);
  gload_lds16(pB + 32 * 4096, dA + 16384 + 8192);
  gload_lds16(pA + 32, dA + 32768);
  gload_lds16(pA + 128 * 4096 + 32, dA + 32768 + 8192);
  gload_lds16(pB + 32, dA + 49152);
  gload_lds16(pB + 32 * 4096 + 32, dA + 49152 + 8192);
  WAITV(4);
  SBAR();

  bf16x8 a1[4], a2[4], bf_[4];

  for (int t = 0; t < NT - 1; ++t) {
    int b = t & 1;
    unsigned bufo = b ? 65536u : 0u;
    char* nD = dA + (b ? 0 : 65536);   // dest = buffer b^1
    unsigned aAdr = aB0 + bufo;
    unsigned bAdr = bB0 + bufo;
    int k1 = (t + 1) * 64;

    // ======== cluster 1 : K 0..31 (parts 0,1) ========
    READ_CLUSTER(aAdr, bAdr);
    gload_lds16(pA + k1, nD);
    gload_lds16(pA + 128 * 4096 + k1, nD + 8192);
    WAITL(4);                           // a1, bf_ ready; a2 still in flight
    __builtin_amdgcn_s_setprio(1);
    MFMA_HALF(a1, 0);
    __builtin_amdgcn_s_setprio(0);
    gload_lds16(pB + k1, nD + 16384);
    gload_lds16(pB + 32 * 4096 + k1, nD + 16384 + 8192);
    WAITL(0);
    __builtin_amdgcn_s_setprio(1);
    MFMA_HALF(a2, 4);
    __builtin_amdgcn_s_setprio(0);
    WAITV(4);                           // drains prev-iter stages = THIS tile's A1,B1
    SBAR();

    // ======== cluster 2 : K 32..63 (parts 2,3) ========
    READ_CLUSTER(aAdr + 32768u, bAdr + 32768u);
    gload_lds16(pA + k1 + 32, nD + 32768);
    gload_lds16(pA + 128 * 4096 + k1 + 32, nD + 32768 + 8192);
    WAITL(4);
    __builtin_amdgcn_s_setprio(1);
    MFMA_HALF(a1, 0);
    __builtin_amdgcn_s_setprio(0);
    gload_lds16(pB + k1 + 32, nD + 49152);
    gload_lds16(pB + 32 * 4096 + k1 + 32, nD + 49152 + 8192);
    WAITL(0);
    __builtin_amdgcn_s_setprio(1);
    MFMA_HALF(a2, 4);
    __builtin_amdgcn_s_setprio(0);
    WAITV(4);                           // drains this iter's A0',B0' = next tile's c1 parts
    SBAR();
  }

  // ---- peeled last tile (t=NT-1, buffer 1): no staging
  {
    unsigned aAdr = aB0 + 65536u;
    unsigned bAdr = bB0 + 65536u;
    READ_CLUSTER(aAdr, bAdr);
    WAITL(4);
    MFMA_HALF(a1, 0);
    WAITL(0);
    MFMA_HALF(a2, 4);
    WAITV(0);                           // last A1,B1 stages must land
    SBAR();
    READ_CLUSTER(aAdr + 32768u, bAdr + 32768u);
    WAITL(4);
    MFMA_HALF(a1, 0);
    WAITL(0);
    MFMA_HALF(a2, 4);
  }

  // ---- epilogue: all 4 gates (n-index) for (m, j) are thread-local
  int j = bn * 64 + wc * 16 + lrow;
  float bi = bias_i[j], bff = bias_f[j], bgg = bias_g[j], bo = bias_o[j];
  int rbase = m0 + wr * 128 + qh * 4;
  #pragma unroll
  for (int mf = 0; mf < 8; mf++) {
    #pragma unroll
    for (int qq = 0; qq < 4; qq++) {
      int m = rbase + mf * 16 + qq;     // C/D: col=lane&15, row=(lane>>4)*4+qq
      size_t off = (size_t)m * HID + j;
      float gi = acc[mf][0][qq] + bi;
      float gf = acc[mf][1][qq] + bff;
      float gg = acc[mf][2][qq] + bgg;
      float go = acc[mf][3][qq] + bo;
      float iv = 1.f / (1.f + __expf(-gi));
      float fv = 1.f / (1.f + __expf(-gf));
      float gv = tanhf(gg);
      float ov = 1.f / (1.f + __expf(-go));
      float cn = fv * c_in[off] + iv * gv;
      float hn = ov * tanhf(cn);
      out[off] = hn;
      out[(size_t)BATCH * HID + off] = cn;
    }
  }
}

// ---- fallback (no workspace): round-3 verified 128-tile reg-staged kernel
__global__ __launch_bounds__(256) void lstm_gemm_fb(
    const float* __restrict__ x, const float* __restrict__ h,
    const float* __restrict__ wii, const float* __restrict__ wif,
    const float* __restrict__ wig, const float* __restrict__ wio,
    const float* __restrict__ whi, const float* __restrict__ whf,
    const float* __restrict__ whg, const float* __restrict__ who,
    const float* __restrict__ c_in,
    const float* __restrict__ bias_i, const float* __restrict__ bias_f,
    const float* __restrict__ bias_g, const float* __restrict__ bias_o,
    float* __restrict__ out) {
  __shared__ unsigned short Ald[128 * 64];
  __shared__ unsigned short Bld[128 * 64];
  int tid = threadIdx.x;
  int lane = tid & 63;
  int wid = tid >> 6;
  int wr = wid >> 1, wc = wid & 1;
  int bid = blockIdx.x;
  int swz = (bid & 7) * 256 + (bid >> 3);
  int mt = swz & 31;
  int ht = swz >> 5;
  int m0 = mt * 128;
  int j0 = ht * 32;
  f32x4 acc[4][4];
  #pragma unroll
  for (int a = 0; a < 4; a++)
    #pragma unroll
    for (int b = 0; b < 4; b++) acc[a][b] = (f32x4){0.f, 0.f, 0.f, 0.f};
  int lrow = lane & 15;
  int lsw = lrow & 7;
  int qbase = lane >> 4;
  for (int kt = 0; kt < 64; kt++) {
    int k0 = kt * 64;
    const float* Asrc = (k0 < 2048) ? x : h;
    int ka = k0 & 2047;
    #pragma unroll
    for (int i = 0; i < 4; i++) {
      int c = i * 256 + tid;
      int r = c >> 3, cc = c & 7;
      int ccs = cc ^ (r & 7);
      const float* s = Asrc + (size_t)(m0 + r) * 2048 + ka + ccs * 8;
      float4 v0 = *(const float4*)s;
      float4 v1 = *(const float4*)(s + 4);
      bf16x8 pk;
      pk[0] = (short)f2bf(v0.x); pk[1] = (short)f2bf(v0.y);
      pk[2] = (short)f2bf(v0.z); pk[3] = (short)f2bf(v0.w);
      pk[4] = (short)f2bf(v1.x); pk[5] = (short)f2bf(v1.y);
      pk[6] = (short)f2bf(v1.z); pk[7] = (short)f2bf(v1.w);
      *(bf16x8*)((char*)Ald + (size_t)c * 16) = pk;
    }
    #pragma unroll
    for (int i = 0; i < 4; i++) {
      int c = i * 256 + tid;
      int rb = c >> 3, cc = c & 7;
      int ccs = cc ^ (rb & 7);
      int g = rb >> 5, jj = rb & 31;
      const float* Bsrc;
      if (k0 < 2048) Bsrc = (g == 0) ? wii : (g == 1) ? wif : (g == 2) ? wig : wio;
      else           Bsrc = (g == 0) ? whi : (g == 1) ? whf : (g == 2) ? whg : who;
      const float* s = Bsrc + (size_t)(j0 + jj) * 2048 + ka + ccs * 8;
      float4 v0 = *(const float4*)s;
      float4 v1 = *(const float4*)(s + 4);
      bf16x8 pk;
      pk[0] = (short)f2bf(v0.x); pk[1] = (short)f2bf(v0.y);
      pk[2] = (short)f2bf(v0.z); pk[3] = (short)f2bf(v0.w);
      pk[4] = (short)f2bf(v1.x); pk[5] = (short)f2bf(v1.y);
      pk[6] = (short)f2bf(v1.z); pk[7] = (short)f2bf(v1.w);
      *(bf16x8*)((char*)Bld + (size_t)c * 16) = pk;
    }
    __syncthreads();
    #pragma unroll
    for (int ks = 0; ks < 2; ks++) {
      int q = ks * 4 + qbase;
      int qs8 = (q ^ lsw) * 8;
      bf16x8 af[4], bg[4];
      #pragma unroll
      for (int mf = 0; mf < 4; mf++)
        af[mf] = *(const bf16x8*)&Ald[(wr * 64 + mf * 16 + lrow) * 64 + qs8];
      #pragma unroll
      for (int g = 0; g < 4; g++)
        bg[g] = *(const bf16x8*)&Bld[(g * 32 + wc * 16 + lrow) * 64 + qs8];
      #pragma unroll
      for (int mf = 0; mf < 4; mf++)
        #pragma unroll
        for (int g = 0; g < 4; g++)
          acc[mf][g] = __builtin_amdgcn_mfma_f32_16x16x32_bf16(af[mf], bg[g], acc[mf][g], 0, 0, 0);
    }
    __syncthreads();
  }
  int j = j0 + wc * 16 + lrow;
  float bi = bias_i[j], bff = bias_f[j], bgg = bias_g[j], bo = bias_o[j];
  int rbase = m0 + wr * 64 + (lane >> 4) * 4;
  #pragma unroll
  for (int mf = 0; mf < 4; mf++) {
    #pragma unroll
    for (int q = 0; q < 4; q++) {
      int m = rbase + mf * 16 + q;
      size_t off = (size_t)m * HID + j;
      float gi = acc[mf][0][q] + bi;
      float gf = acc[mf][1][q] + bff;
      float gg = acc[mf][2][q] + bgg;
      float go = acc[mf][3][q] + bo;
      float iv = 1.f / (1.f + __expf(-gi));
      float fv = 1.f / (1.f + __expf(-gf));
      float gv = tanhf(gg);
      float ov = 1.f / (1.f + __expf(-go));
      float cn = fv * c_in[off] + iv * gv;
      float hn = ov * tanhf(cn);
      out[off] = hn;
      out[(size_t)BATCH * HID + off] = cn;
    }
  }
}

extern "C" void kernel_launch(void* const* d_in, const int* in_sizes, int n_in,
                              void* d_out, int out_size, void* d_ws, size_t ws_size,
                              hipStream_t stream) {
  const float* x   = (const float*)d_in[0];
  const float* h   = (const float*)d_in[1];
  const float* c   = (const float*)d_in[2];
  const float* wii = (const float*)d_in[3];
  const float* wif = (const float*)d_in[4];
  const float* wig = (const float*)d_in[5];
  const float* wio = (const float*)d_in[6];
  const float* whi = (const float*)d_in[7];
  const float* whf = (const float*)d_in[8];
  const float* whg = (const float*)d_in[9];
  const float* who = (const float*)d_in[10];
  const float* bi  = (const float*)d_in[11];
  const float* bf  = (const float*)d_in[12];
  const float* bg  = (const float*)d_in[13];
  const float* bo  = (const float*)d_in[14];
  float* out = (float*)d_out;

  size_t needA = (size_t)4096 * 4096 * 2;
  size_t needW = (size_t)8192 * 4096 * 2;

  if (ws_size >= needA + needW) {
    unsigned short* Abf = (unsigned short*)d_ws;
    unsigned short* Wbf = (unsigned short*)((char*)d_ws + needA);
    convert_kernel<<<dim3(4096, 12), 256, 0, stream>>>(
        x, h, wii, wif, wig, wio, whi, whf, whg, who, Abf, Wbf);
    lstm_gemm8<<<512, 512, 0, stream>>>(Abf, Wbf, c, bi, bf, bg, bo, out);
  } else {
    lstm_gemm_fb<<<2048, 256, 0, stream>>>(
        x, h, wii, wif, wig, wio, whi, whf, whg, who,
        c, bi, bf, bg, bo, out);
  }
}